// Round 10
// baseline (209.676 us; speedup 1.0000x reference)
//
#include <hip/hip_runtime.h>

// Problem constants
#define B_  2
#define N_  2048
#define M_  2048
#define D_  1024
#define H_  16
#define DH_ 64

typedef __bf16 bf16x8 __attribute__((ext_vector_type(8)));
typedef __bf16 bf16x4 __attribute__((ext_vector_type(4)));
typedef short  short4v __attribute__((ext_vector_type(4)));
typedef float  f32x4  __attribute__((ext_vector_type(4)));
typedef unsigned int u32x4v __attribute__((ext_vector_type(4)));

#define GAS(p) ((__attribute__((address_space(1))) void*)(p))
#define LAS(p) ((__attribute__((address_space(3))) void*)(p))

// SCALE * log2(e), folded into Q at projection time
#define QPRESCALE 0.18033688011112042f

__device__ __forceinline__ unsigned short f2bf(float f) {
    unsigned int u = __builtin_bit_cast(unsigned int, f);
    u += 0x7fffu + ((u >> 16) & 1u);   // round-to-nearest-even
    return (unsigned short)(u >> 16);
}

// pack two f32 -> one u32 of 2 bf16 (lo = a, hi = b), RNE
__device__ __forceinline__ unsigned cvtpkbf(float a, float b) {
    unsigned r;
    asm("v_cvt_pk_bf16_f32 %0, %1, %2" : "=v"(r) : "v"(a), "v"(b));
    return r;
}

// ------- kernel 1: prep = weight transpose+cast (z<4) | input cast (z==4) -------
__global__ __launch_bounds__(256) void prep(
    const float* __restrict__ x, const float* __restrict__ ctx,
    const float* __restrict__ Wq, const float* __restrict__ Wk,
    const float* __restrict__ Wv, const float* __restrict__ Wo,
    unsigned short* __restrict__ xb, unsigned short* __restrict__ cb,
    unsigned short* __restrict__ WTbase)
{
    if (blockIdx.z == 4) {
        int blk = blockIdx.y * 32 + blockIdx.x;
        int stride = 1024 * 256;
        for (int i = blk * 256 + threadIdx.x; i < 2097152; i += stride) {
            const float4* src; unsigned short* dst; int j;
            if (i < 1048576) { src = (const float4*)x;   dst = xb; j = i; }
            else             { src = (const float4*)ctx; dst = cb; j = i - 1048576; }
            float4 v = src[j];
            ushort4 o = make_ushort4(f2bf(v.x), f2bf(v.y), f2bf(v.z), f2bf(v.w));
            *(ushort4*)(dst + 4*j) = o;
        }
        return;
    }
    const float* W = (blockIdx.z == 0) ? Wq : (blockIdx.z == 1) ? Wk
                    : (blockIdx.z == 2) ? Wv : Wo;
    unsigned short* WT = WTbase + (size_t)blockIdx.z * 1048576;
    __shared__ unsigned short t[32][33];
    int tx = threadIdx.x & 31, ty8 = threadIdx.x >> 5;   // 32 x 8
    int c = blockIdx.x * 32 + tx;
#pragma unroll
    for (int i = 0; i < 4; ++i) {
        int r = blockIdx.y * 32 + i*8 + ty8;
        t[i*8 + ty8][tx] = f2bf(W[(size_t)r * 1024 + c]);
    }
    __syncthreads();
    int c2 = blockIdx.y * 32 + tx;
#pragma unroll
    for (int i = 0; i < 4; ++i) {
        int r2 = blockIdx.x * 32 + i*8 + ty8;
        WT[(size_t)r2 * 1024 + c2] = t[tx][i*8 + ty8];
    }
}

// ---------------- kernel 2: 128x128 bf16 GEMM, C = A * Bt^T (QKV modes) -------
// ROUND-10 CHANGE (2-phase pipeline): the old loop was stage -> full-drain
// __syncthreads -> compute, exposing the entire L2/L3 load latency every
// K-step (only 3-blocks/CU TLP to cover it; small-K GEMMs live in the
// latency-dominated part of the shape curve).  Now BK=32 double-buffered:
// issue tile t+1's global_load_lds BEFORE computing tile t; the barrier
// drain at iter end lands after ~300cyc of ds_read+MFMA has covered the
// load latency.  Same 32 KB LDS, same occupancy, same barrier count, K
// strictly ascending -> bit-identical summation order.
// XCD swizzle (round-8): 3 (mode,y) panels x 32 token tiles per XCD.
// mode 0: A=WqT, Bt=xb  -> Q^T tile, stored [B,H,N,64] bf16 (*QPRESCALE), ushort4
// mode 1: A=WkT, Bt=cb  -> K^T tile, stored [B,H,M,64] bf16, ushort4
// mode 2: A=cb,  Bt=WvT -> V^T stored [B,H,64,M] bf16, ushort4 (original swap)
__global__ __launch_bounds__(256) void gemm128(
    const unsigned short* __restrict__ xb,
    const unsigned short* __restrict__ cb,
    const unsigned short* __restrict__ wT,
    const unsigned short* __restrict__ aoA,
    unsigned short* __restrict__ qkv_out,
    const float* __restrict__ bo,
    float* __restrict__ outF,
    int base_mode)
{
    __shared__ __align__(16) unsigned short As[2][128*32];
    __shared__ __align__(16) unsigned short Bs[2][128*32];

    const int lin = (blockIdx.z * 8 + blockIdx.y) * 32 + blockIdx.x;
    const int idx = lin >> 3;
    const int p = (lin & 7) * 3 + (idx >> 5);
    const int mode = base_mode + (p >> 3);
    const int ytile = p & 7, xtile = idx & 31;

    const unsigned short* Amat;
    const unsigned short* Bt;
    if (mode == 0)      { Amat = wT;               Bt = xb; }
    else if (mode == 1) { Amat = wT + 1048576;     Bt = cb; }
    else                { Amat = cb;               Bt = wT + 2*1048576; }

    const int tid = threadIdx.x;
    const int w = tid >> 6, l = tid & 63;
    const int quad = l >> 4, l16 = l & 15;
    const int wm = w & 1, wn = w >> 1;
    int row0, col0;
    if (mode == 2) { row0 = xtile * 128; col0 = ytile * 128; }
    else           { row0 = ytile * 128; col0 = xtile * 128; }

    f32x4 acc[4][4];
#pragma unroll
    for (int i = 0; i < 4; ++i)
#pragma unroll
        for (int j = 0; j < 4; ++j) acc[i][j] = (f32x4){0.f, 0.f, 0.f, 0.f};

    // stage one BK=32 tile pair into buffer b (4 global_load_lds / thread)
    auto stage = [&](int k0, int b) {
#pragma unroll
        for (int i = 0; i < 2; ++i) {
            int s = i*256 + w*64 + l;
            int m = s >> 2, c = s & 3;
            int cs = c ^ ((m >> 1) & 3);
            __builtin_amdgcn_global_load_lds(
                GAS(Amat + (size_t)(row0 + m)*1024 + k0 + cs*8),
                LAS(As[b] + (i*256 + w*64)*8), 16, 0, 0);
            __builtin_amdgcn_global_load_lds(
                GAS(Bt + (size_t)(col0 + m)*1024 + k0 + cs*8),
                LAS(Bs[b] + (i*256 + w*64)*8), 16, 0, 0);
        }
    };

    stage(0, 0);
    __syncthreads();                       // tile 0 ready

    for (int t = 0; t < 32; ++t) {
        const int cur = t & 1;
        if (t + 1 < 32) stage((t + 1) * 32, cur ^ 1);   // in-flight during compute

        bf16x8 af[4], bfr[4];
#pragma unroll
        for (int mt = 0; mt < 4; ++mt) {
            int m = wm*64 + mt*16 + l16;
            af[mt] = *reinterpret_cast<const bf16x8*>(As[cur] + m*32 + (quad ^ ((m >> 1) & 3))*8);
            int n = wn*64 + mt*16 + l16;
            bfr[mt] = *reinterpret_cast<const bf16x8*>(Bs[cur] + n*32 + (quad ^ ((n >> 1) & 3))*8);
        }
#pragma unroll
        for (int mt = 0; mt < 4; ++mt)
#pragma unroll
            for (int nt = 0; nt < 4; ++nt)
                acc[mt][nt] = __builtin_amdgcn_mfma_f32_16x16x32_bf16(
                    af[mt], bfr[nt], acc[mt][nt], 0, 0, 0);

        __syncthreads();                   // drains next tile's loads post-compute
    }

    // Epilogues.  C/D layout: col = l16, row = quad*4 + r  [m89/m91 verified]
    if (mode == 2) {
        // V^T: [B,H,64,M]; r-direction = token n -> ushort4
#pragma unroll
        for (int mt = 0; mt < 4; ++mt) {
            int gr = row0 + wm*64 + mt*16 + quad*4;
            int b = gr >> 11, nidx = gr & 2047;
#pragma unroll
            for (int nt = 0; nt < 4; ++nt) {
                int col = col0 + wn*64 + nt*16 + l16;
                int h = col >> 6, d = col & 63;
                ushort4 pk = make_ushort4(f2bf(acc[mt][nt][0]), f2bf(acc[mt][nt][1]),
                                          f2bf(acc[mt][nt][2]), f2bf(acc[mt][nt][3]));
                *(ushort4*)(qkv_out + (size_t)2*4194304
                            + (size_t)((b*16 + h)*64 + d)*2048 + nidx) = pk;
            }
        }
    } else {
        // Q^T/K^T tile: row = channel c=(h,d) (4 consecutive d), col = token n
        const float qs = (mode == 0) ? QPRESCALE : 1.0f;
        unsigned short* obase = qkv_out + (size_t)mode*4194304;
#pragma unroll
        for (int nt = 0; nt < 4; ++nt) {
            int n = col0 + wn*64 + nt*16 + l16;
            int b = n >> 11, nidx = n & 2047;
#pragma unroll
            for (int mt = 0; mt < 4; ++mt) {
                int c = row0 + wm*64 + mt*16 + quad*4;
                int h = c >> 6, d = c & 63;
                ushort4 pkv = make_ushort4(
                    f2bf(acc[mt][nt][0] * qs), f2bf(acc[mt][nt][1] * qs),
                    f2bf(acc[mt][nt][2] * qs), f2bf(acc[mt][nt][3] * qs));
                *(ushort4*)(obase + (size_t)((b*16 + h)*2048 + nidx)*64 + d) = pkv;
            }
        }
    }
}

// ---------------- kernel 2b: out-projection GEMM, 64x128 tile -----------------
// ROUND-10: same 2-phase BK=32 double-buffered pipeline as gemm128.
// XCD swizzle (round-8): 2 channel-tiles x 32 token tiles per XCD.
__global__ __launch_bounds__(256) void gemm_out(
    const unsigned short* __restrict__ woT,  // [1024 out-ch][1024 in] bf16
    const unsigned short* __restrict__ aoA,  // [4096 tokens][1024] bf16
    const float* __restrict__ bo,
    float* __restrict__ outF)                // [4096 tokens][1024] f32
{
    __shared__ __align__(16) unsigned short As[2][64*32];
    __shared__ __align__(16) unsigned short Bs[2][128*32];

    const int tid = threadIdx.x;
    const int w = tid >> 6, l = tid & 63;
    const int quad = l >> 4, l16 = l & 15;
    const int lin = blockIdx.y * 32 + blockIdx.x;
    const int idx = lin >> 3;
    const int row0 = ((lin & 7) * 2 + (idx >> 5)) * 64;  // out-channel tile
    const int col0 = (idx & 31) * 128;                   // token tile

    f32x4 acc[4][2];
#pragma unroll
    for (int i = 0; i < 4; ++i)
#pragma unroll
        for (int j = 0; j < 2; ++j) acc[i][j] = (f32x4){0.f, 0.f, 0.f, 0.f};

    auto stage = [&](int k0, int b) {
        {
            int m = tid >> 2, c = tid & 3;
            int cs = c ^ ((m >> 1) & 3);
            __builtin_amdgcn_global_load_lds(
                GAS(woT + (size_t)(row0 + m)*1024 + k0 + cs*8),
                LAS(As[b] + (w*64)*8), 16, 0, 0);
        }
#pragma unroll
        for (int i = 0; i < 2; ++i) {
            int s = i*256 + tid;
            int m = s >> 2, c = s & 3;
            int cs = c ^ ((m >> 1) & 3);
            __builtin_amdgcn_global_load_lds(
                GAS(aoA + (size_t)(col0 + m)*1024 + k0 + cs*8),
                LAS(Bs[b] + (i*256 + w*64)*8), 16, 0, 0);
        }
    };

    stage(0, 0);
    __syncthreads();

    for (int t = 0; t < 32; ++t) {
        const int cur = t & 1;
        if (t + 1 < 32) stage((t + 1) * 32, cur ^ 1);

        bf16x8 af[4], bfr[2];
#pragma unroll
        for (int mt = 0; mt < 4; ++mt) {
            int m = mt*16 + l16;
            af[mt] = *reinterpret_cast<const bf16x8*>(As[cur] + m*32 + (quad ^ ((m >> 1) & 3))*8);
        }
#pragma unroll
        for (int nt = 0; nt < 2; ++nt) {
            int n = w*32 + nt*16 + l16;
            bfr[nt] = *reinterpret_cast<const bf16x8*>(Bs[cur] + n*32 + (quad ^ ((n >> 1) & 3))*8);
        }
#pragma unroll
        for (int mt = 0; mt < 4; ++mt)
#pragma unroll
            for (int nt = 0; nt < 2; ++nt)
                acc[mt][nt] = __builtin_amdgcn_mfma_f32_16x16x32_bf16(
                    af[mt], bfr[nt], acc[mt][nt], 0, 0, 0);

        __syncthreads();
    }

#pragma unroll
    for (int mt = 0; mt < 4; ++mt) {
        int c = row0 + mt*16 + quad*4;
        float4 bv = *(const float4*)(bo + c);
#pragma unroll
        for (int nt = 0; nt < 2; ++nt) {
            int n = col0 + w*32 + nt*16 + l16;
            float4 ov = make_float4(acc[mt][nt][0] + bv.x, acc[mt][nt][1] + bv.y,
                                    acc[mt][nt][2] + bv.z, acc[mt][nt][3] + bv.w);
            *(float4*)(outF + (size_t)n*1024 + c) = ov;
        }
    }
}

// ---------------- kernel 3: flash attention (round-8 config, FROZEN) -----------
// Best measured: 50.28us (r8).  q-tile 128 (4 waves), kv-split (wave w owns
// q-half w&1 and kv-half w>>1; LDS reads halved), XCD swizzle (FETCH 69.7 ->
// 12.3 MB), 2 blocks/CU.  Declared converged: dependency-chain-bound
// (MFMA->exp2->permlane->PV + per-iter barrier skew); every resource knob
// measured over-provisioned.
// FAILED VARIANTS (do not retry): counted-vmcnt/3-buf (r2 null), 64q/wave in
// 2-wave blocks (r3 +22%), LDS-free reg-direct K/V (r5 +137%), q-tile 64 at
// 4 blocks/CU (r9 +1us, absmax worse).
__global__ __launch_bounds__(256, 2) void flash_attn(
    const unsigned short* __restrict__ qw,   // [B,H,N,64]  (pre-scaled)
    const unsigned short* __restrict__ kw,   // [B,H,M,64]
    const unsigned short* __restrict__ vtw,  // [B,H,64,M]
    unsigned short* __restrict__ ao)         // [B,N,H*64]
{
    __shared__ __align__(16) unsigned short Tile[2][9216];  // 2 x 18432 B

    const int tid = threadIdx.x;
    const int w = tid >> 6, l = tid & 63;
    const int quad = l >> 4, l16 = l & 15;
    // XCD-aware remap (grid (16,16,2) -> lin in [0,512))
    const int lin = (blockIdx.z * 16 + blockIdx.y) * 16 + blockIdx.x;
    const int bh = (lin & 7) * 4 + (lin >> 7);
    const int qt = (lin >> 3) & 15;
    const int qh = w & 1, kvh = w >> 1;
    const int q0 = qt * 128 + qh * 64;   // this wave's 64 queries

    int goff[5];
#pragma unroll
    for (int i = 0; i < 5; ++i) {
        int n = i*256 + w*64 + l;
        int m = (n < 576) ? n : n - 576;
        int row = m / 9, c = m % 9;  if (c > 7) c = 7;     // clamp pad chunk
        goff[i] = (n < 576) ? row*64 + c*8 : row*2048 + c*8;
    }
    const unsigned short* kbase = kw + (size_t)bh*131072;
    const unsigned short* vbase = vtw + (size_t)bh*131072;

    // Q as B-frag (K=32): B[n=q][k=d]; four 16-q groups
    bf16x8 qf[4][2];
#pragma unroll
    for (int qg = 0; qg < 4; ++qg)
#pragma unroll
        for (int s = 0; s < 2; ++s)
            qf[qg][s] = *reinterpret_cast<const bf16x8*>(
                qw + (size_t)(bh*2048 + q0 + qg*16 + l16)*64 + s*32 + quad*8);

    f32x4 accO[4][4];
#pragma unroll
    for (int qg = 0; qg < 4; ++qg)
#pragma unroll
        for (int td = 0; td < 4; ++td) accO[qg][td] = (f32x4){0.f, 0.f, 0.f, 0.f};
    float lpart[4] = {0.f, 0.f, 0.f, 0.f};

    const f32x4 zz = (f32x4){0.f, 0.f, 0.f, 0.f};

    // ---- preload tile 0 into buf 0
    {
#pragma unroll
        for (int i = 0; i < 4; ++i) {
            const unsigned short* bp = (i*4 + w < 9) ? kbase : vbase;
            __builtin_amdgcn_global_load_lds(GAS(bp + goff[i]),
                LAS(&Tile[0][(i*256 + w*64)*8]), 16, 0, 0);
        }
        if (w < 2)
            __builtin_amdgcn_global_load_lds(GAS(vbase + goff[4]),
                LAS(&Tile[0][(1024 + w*64)*8]), 16, 0, 0);
    }

    for (int it = 0; it < 32; ++it) {
        __syncthreads();   // drains vmcnt -> Tile[it&1] ready
        const int cur = it & 1;

        if (it + 1 < 32) {
            const unsigned short* kp = kbase + (it+1)*4096;
            const unsigned short* vp = vbase + (it+1)*64;
#pragma unroll
            for (int i = 0; i < 4; ++i) {
                const unsigned short* bp = (i*4 + w < 9) ? kp : vp;
                __builtin_amdgcn_global_load_lds(GAS(bp + goff[i]),
                    LAS(&Tile[cur^1][(i*256 + w*64)*8]), 16, 0, 0);
            }
            if (w < 2)
                __builtin_amdgcn_global_load_lds(GAS(vp + goff[4]),
                    LAS(&Tile[cur^1][(1024 + w*64)*8]), 16, 0, 0);
        }

        const unsigned short* Ks = &Tile[cur][0];
        const unsigned short* Vs = &Tile[cur][4608];

        // S^T = K Q^T over this wave's 32 kv rows: t = 0,1 (16 rows each)
        f32x4 sac[4][2];
        __builtin_amdgcn_s_setprio(1);
#pragma unroll
        for (int t = 0; t < 2; ++t) {
            const unsigned short* krow = Ks + (kvh*32 + t*16 + l16)*72 + quad*8;
            bf16x8 kf0 = *reinterpret_cast<const bf16x8*>(krow);
            bf16x8 kf1 = *reinterpret_cast<const bf16x8*>(krow + 32);
#pragma unroll
            for (int qg = 0; qg < 4; ++qg) {
                sac[qg][t] = __builtin_amdgcn_mfma_f32_16x16x32_bf16(kf0, qf[qg][0], zz, 0, 0, 0);
                sac[qg][t] = __builtin_amdgcn_mfma_f32_16x16x32_bf16(kf1, qf[qg][1], sac[qg][t], 0, 0, 0);
            }
        }
        __builtin_amdgcn_s_setprio(0);

        // P^T = exp2(S^T); fp32 partial row-sums; build one K=32 B-frag per qg
        u32x4v pB[4];
#pragma unroll
        for (int qg = 0; qg < 4; ++qg) {
            float pe0 = __builtin_amdgcn_exp2f(sac[qg][0][0]);
            float pe1 = __builtin_amdgcn_exp2f(sac[qg][0][1]);
            float pe2 = __builtin_amdgcn_exp2f(sac[qg][0][2]);
            float pe3 = __builtin_amdgcn_exp2f(sac[qg][0][3]);
            float po0 = __builtin_amdgcn_exp2f(sac[qg][1][0]);
            float po1 = __builtin_amdgcn_exp2f(sac[qg][1][1]);
            float po2 = __builtin_amdgcn_exp2f(sac[qg][1][2]);
            float po3 = __builtin_amdgcn_exp2f(sac[qg][1][3]);
            lpart[qg] += ((pe0 + po0) + (pe1 + po1)) + ((pe2 + po2) + (pe3 + po3));
            unsigned b0 = cvtpkbf(pe0, pe1), b1 = cvtpkbf(pe2, pe3);
            unsigned b2 = cvtpkbf(po0, po1), b3 = cvtpkbf(po2, po3);
            asm("v_permlane32_swap_b32 %0, %1" : "+v"(b0), "+v"(b2));
            asm("v_permlane16_swap_b32 %0, %1" : "+v"(b0), "+v"(b2));
            asm("v_permlane32_swap_b32 %0, %1" : "+v"(b1), "+v"(b3));
            asm("v_permlane16_swap_b32 %0, %1" : "+v"(b1), "+v"(b3));
            pB[qg] = (u32x4v){b0, b1, b2, b3};
        }

        // O^T += V^T P^T over this wave's 32 kv cols (k = kvh*32 + quad*8 + e)
        __builtin_amdgcn_s_setprio(1);
#pragma unroll
        for (int td = 0; td < 4; ++td) {
            bf16x8 vf = *reinterpret_cast<const bf16x8*>(
                Vs + (td*16 + l16)*72 + kvh*32 + quad*8);
#pragma unroll
            for (int qg = 0; qg < 4; ++qg)
                accO[qg][td] = __builtin_amdgcn_mfma_f32_16x16x32_bf16(
                    vf, __builtin_bit_cast(bf16x8, pB[qg]), accO[qg][td], 0, 0, 0);
        }
        __builtin_amdgcn_s_setprio(0);
    }

    // ---- cross-pair (kv-half) reduction through the dead Tile buffer.
    float* xch = (float*)&Tile[0][0];
    __syncthreads();   // all waves done reading Tile
    if (kvh == 1) {
        float* base = xch + (size_t)(qh*64 + l)*72;
#pragma unroll
        for (int qg = 0; qg < 4; ++qg)
#pragma unroll
            for (int td = 0; td < 4; ++td)
                *(f32x4*)(base + (qg*4 + td)*4) = accO[qg][td];
        *(f32x4*)(base + 64) = (f32x4){lpart[0], lpart[1], lpart[2], lpart[3]};
    }
    __syncthreads();
    if (kvh == 0) {
        const float* base = xch + (size_t)(qh*64 + l)*72;
#pragma unroll
        for (int qg = 0; qg < 4; ++qg)
#pragma unroll
            for (int td = 0; td < 4; ++td)
                accO[qg][td] += *(const f32x4*)(base + (qg*4 + td)*4);
        f32x4 lp2 = *(const f32x4*)(base + 64);
        lpart[0] += lp2[0]; lpart[1] += lp2[1];
        lpart[2] += lp2[2]; lpart[3] += lp2[3];

        // normalize + store this wave's 64 q rows
        const int bb = bh >> 4, hh = bh & 15;
#pragma unroll
        for (int qg = 0; qg < 4; ++qg) {
            float s = lpart[qg];
            s += __shfl_xor(s, 16);
            s += __shfl_xor(s, 32);
            float inv = 1.f / s;
            const size_t rowbase =
                (size_t)(bb*2048 + q0 + qg*16 + l16)*1024 + hh*64;
#pragma unroll
            for (int td = 0; td < 4; ++td)
#pragma unroll
                for (int r = 0; r < 4; ++r)
                    ao[rowbase + td*16 + quad*4 + r] = f2bf(accO[qg][td][r] * inv);
        }
    }
}

extern "C" void kernel_launch(void* const* d_in, const int* in_sizes, int n_in,
                              void* d_out, int out_size, void* d_ws, size_t ws_size,
                              hipStream_t stream)
{
    const float* x   = (const float*)d_in[0];
    const float* ctx = (const float*)d_in[1];
    const float* Wq  = (const float*)d_in[2];
    const float* Wk  = (const float*)d_in[3];
    const float* Wv  = (const float*)d_in[4];
    const float* Wo  = (const float*)d_in[5];
    const float* bo  = (const float*)d_in[6];
    float* out = (float*)d_out;

    unsigned short* ws  = (unsigned short*)d_ws;
    unsigned short* xb  = ws;
    unsigned short* cb  = ws + 4194304;
    unsigned short* wT  = ws + 8388608;
    unsigned short* qkv = ws + 12582912;
    unsigned short* ao  = ws;  // reuse xb space (xb dead after projections)

    prep<<<dim3(32, 32, 5), dim3(256), 0, stream>>>(x, ctx, Wq, Wk, Wv, Wo, xb, cb, wT);
    gemm128<<<dim3(32, 8, 3), dim3(256), 0, stream>>>(xb, cb, wT, ao, qkv, bo, out, 0);
    flash_attn<<<dim3(16, 16, 2), dim3(256), 0, stream>>>(qkv, qkv + 4194304, qkv + 8388608, ao);
    gemm_out<<<dim3(32, 16), dim3(256), 0, stream>>>(wT + 3*1048576, ao, bo, out);
}

// Round 11
// 200.113 us; speedup vs baseline: 1.0478x; 1.0478x over previous
//
#include <hip/hip_runtime.h>

// Problem constants
#define B_  2
#define N_  2048
#define M_  2048
#define D_  1024
#define H_  16
#define DH_ 64

typedef __bf16 bf16x8 __attribute__((ext_vector_type(8)));
typedef __bf16 bf16x4 __attribute__((ext_vector_type(4)));
typedef short  short4v __attribute__((ext_vector_type(4)));
typedef float  f32x4  __attribute__((ext_vector_type(4)));
typedef unsigned int u32x4v __attribute__((ext_vector_type(4)));

#define GAS(p) ((__attribute__((address_space(1))) void*)(p))
#define LAS(p) ((__attribute__((address_space(3))) void*)(p))

// SCALE * log2(e), folded into Q at projection time
#define QPRESCALE 0.18033688011112042f

__device__ __forceinline__ unsigned short f2bf(float f) {
    unsigned int u = __builtin_bit_cast(unsigned int, f);
    u += 0x7fffu + ((u >> 16) & 1u);   // round-to-nearest-even
    return (unsigned short)(u >> 16);
}

// pack two f32 -> one u32 of 2 bf16 (lo = a, hi = b), RNE
__device__ __forceinline__ unsigned cvtpkbf(float a, float b) {
    unsigned r;
    asm("v_cvt_pk_bf16_f32 %0, %1, %2" : "=v"(r) : "v"(a), "v"(b));
    return r;
}

// ------- kernel 1: prep = weight transpose+cast (z<4) | input cast (z==4) -------
__global__ __launch_bounds__(256) void prep(
    const float* __restrict__ x, const float* __restrict__ ctx,
    const float* __restrict__ Wq, const float* __restrict__ Wk,
    const float* __restrict__ Wv, const float* __restrict__ Wo,
    unsigned short* __restrict__ xb, unsigned short* __restrict__ cb,
    unsigned short* __restrict__ WTbase)
{
    if (blockIdx.z == 4) {
        int blk = blockIdx.y * 32 + blockIdx.x;
        int stride = 1024 * 256;
        for (int i = blk * 256 + threadIdx.x; i < 2097152; i += stride) {
            const float4* src; unsigned short* dst; int j;
            if (i < 1048576) { src = (const float4*)x;   dst = xb; j = i; }
            else             { src = (const float4*)ctx; dst = cb; j = i - 1048576; }
            float4 v = src[j];
            ushort4 o = make_ushort4(f2bf(v.x), f2bf(v.y), f2bf(v.z), f2bf(v.w));
            *(ushort4*)(dst + 4*j) = o;
        }
        return;
    }
    const float* W = (blockIdx.z == 0) ? Wq : (blockIdx.z == 1) ? Wk
                    : (blockIdx.z == 2) ? Wv : Wo;
    unsigned short* WT = WTbase + (size_t)blockIdx.z * 1048576;
    __shared__ unsigned short t[32][33];
    int tx = threadIdx.x & 31, ty8 = threadIdx.x >> 5;   // 32 x 8
    int c = blockIdx.x * 32 + tx;
#pragma unroll
    for (int i = 0; i < 4; ++i) {
        int r = blockIdx.y * 32 + i*8 + ty8;
        t[i*8 + ty8][tx] = f2bf(W[(size_t)r * 1024 + c]);
    }
    __syncthreads();
    int c2 = blockIdx.y * 32 + tx;
#pragma unroll
    for (int i = 0; i < 4; ++i) {
        int r2 = blockIdx.x * 32 + i*8 + ty8;
        WT[(size_t)r2 * 1024 + c2] = t[tx][i*8 + ty8];
    }
}

// ---------------- kernel 2: 128x128 bf16 GEMM, C = A * Bt^T (QKV modes) -------
// ROUND-11: consolidation revert to the r7 structure (session-best total
// 198.6us): BK=64 -- two 32-wide K sub-tiles staged under one barrier pair
// (halves the vmcnt(0)+lgkmcnt(0) barrier drains vs BK=32), NO XCD swizzle
// (r8's swizzle measured +2us on total), direct blockIdx mapping.
// FAILED GEMM VARIANTS (do not retry): BK=32 2-phase stage-while-compute
// (r10, +9us: __syncthreads drains the just-issued prefetch anyway and the
// compiler may sink the loads -- matches m131/m99 null), XCD swizzle (r8,
// +2us), counted-vmcnt on the 2-barrier structure (documented null, m131).
// mode 0: A=WqT, Bt=xb  -> Q^T tile, stored [B,H,N,64] bf16 (*QPRESCALE), ushort4
// mode 1: A=WkT, Bt=cb  -> K^T tile, stored [B,H,M,64] bf16, ushort4
// mode 2: A=cb,  Bt=WvT -> V^T stored [B,H,64,M] bf16, ushort4 (original swap)
__global__ __launch_bounds__(256) void gemm128(
    const unsigned short* __restrict__ xb,
    const unsigned short* __restrict__ cb,
    const unsigned short* __restrict__ wT,
    const unsigned short* __restrict__ aoA,
    unsigned short* __restrict__ qkv_out,
    const float* __restrict__ bo,
    float* __restrict__ outF,
    int base_mode)
{
    __shared__ __align__(16) unsigned short As[2][128*32];
    __shared__ __align__(16) unsigned short Bs[2][128*32];

    const int mode = base_mode + blockIdx.z;
    const unsigned short* Amat;
    const unsigned short* Bt;
    if (mode == 0)      { Amat = wT;               Bt = xb; }
    else if (mode == 1) { Amat = wT + 1048576;     Bt = cb; }
    else                { Amat = cb;               Bt = wT + 2*1048576; }

    const int tid = threadIdx.x;
    const int w = tid >> 6, l = tid & 63;
    const int quad = l >> 4, l16 = l & 15;
    const int wm = w & 1, wn = w >> 1;
    int row0, col0;
    if (mode == 2) { row0 = blockIdx.x * 128; col0 = blockIdx.y * 128; }
    else           { row0 = blockIdx.y * 128; col0 = blockIdx.x * 128; }

    f32x4 acc[4][4];
#pragma unroll
    for (int i = 0; i < 4; ++i)
#pragma unroll
        for (int j = 0; j < 4; ++j) acc[i][j] = (f32x4){0.f, 0.f, 0.f, 0.f};

    for (int k0 = 0; k0 < 1024; k0 += 64) {
        __syncthreads();
#pragma unroll
        for (int h = 0; h < 2; ++h) {
#pragma unroll
            for (int i = 0; i < 2; ++i) {
                int s = i*256 + w*64 + l;
                int m = s >> 2, c = s & 3;
                int cs = c ^ ((m >> 1) & 3);
                __builtin_amdgcn_global_load_lds(
                    GAS(Amat + (size_t)(row0 + m)*1024 + k0 + h*32 + cs*8),
                    LAS(As[h] + (i*256 + w*64)*8), 16, 0, 0);
                __builtin_amdgcn_global_load_lds(
                    GAS(Bt + (size_t)(col0 + m)*1024 + k0 + h*32 + cs*8),
                    LAS(Bs[h] + (i*256 + w*64)*8), 16, 0, 0);
            }
        }
        __syncthreads();

#pragma unroll
        for (int h = 0; h < 2; ++h) {
            bf16x8 af[4], bfr[4];
#pragma unroll
            for (int mt = 0; mt < 4; ++mt) {
                int m = wm*64 + mt*16 + l16;
                af[mt] = *reinterpret_cast<const bf16x8*>(As[h] + m*32 + (quad ^ ((m >> 1) & 3))*8);
                int n = wn*64 + mt*16 + l16;
                bfr[mt] = *reinterpret_cast<const bf16x8*>(Bs[h] + n*32 + (quad ^ ((n >> 1) & 3))*8);
            }
#pragma unroll
            for (int mt = 0; mt < 4; ++mt)
#pragma unroll
                for (int nt = 0; nt < 4; ++nt)
                    acc[mt][nt] = __builtin_amdgcn_mfma_f32_16x16x32_bf16(
                        af[mt], bfr[nt], acc[mt][nt], 0, 0, 0);
        }
    }

    // Epilogues.  C/D layout: col = l16, row = quad*4 + r  [m89/m91 verified]
    if (mode == 2) {
        // V^T: [B,H,64,M]; r-direction = token n -> ushort4
#pragma unroll
        for (int mt = 0; mt < 4; ++mt) {
            int gr = row0 + wm*64 + mt*16 + quad*4;
            int b = gr >> 11, nidx = gr & 2047;
#pragma unroll
            for (int nt = 0; nt < 4; ++nt) {
                int col = col0 + wn*64 + nt*16 + l16;
                int h = col >> 6, d = col & 63;
                ushort4 pk = make_ushort4(f2bf(acc[mt][nt][0]), f2bf(acc[mt][nt][1]),
                                          f2bf(acc[mt][nt][2]), f2bf(acc[mt][nt][3]));
                *(ushort4*)(qkv_out + (size_t)2*4194304
                            + (size_t)((b*16 + h)*64 + d)*2048 + nidx) = pk;
            }
        }
    } else {
        // Q^T/K^T tile: row = channel c=(h,d) (4 consecutive d), col = token n
        const float qs = (mode == 0) ? QPRESCALE : 1.0f;
        unsigned short* obase = qkv_out + (size_t)mode*4194304;
#pragma unroll
        for (int nt = 0; nt < 4; ++nt) {
            int n = col0 + wn*64 + nt*16 + l16;
            int b = n >> 11, nidx = n & 2047;
#pragma unroll
            for (int mt = 0; mt < 4; ++mt) {
                int c = row0 + wm*64 + mt*16 + quad*4;
                int h = c >> 6, d = c & 63;
                ushort4 pkv = make_ushort4(
                    f2bf(acc[mt][nt][0] * qs), f2bf(acc[mt][nt][1] * qs),
                    f2bf(acc[mt][nt][2] * qs), f2bf(acc[mt][nt][3] * qs));
                *(ushort4*)(obase + (size_t)((b*16 + h)*2048 + nidx)*64 + d) = pkv;
            }
        }
    }
}

// ---------------- kernel 2b: out-projection GEMM, 64x128 tile, BK=64 ----------
// r7 structure (session-best): BK=64 under one barrier pair, no swizzle.
__global__ __launch_bounds__(256) void gemm_out(
    const unsigned short* __restrict__ woT,  // [1024 out-ch][1024 in] bf16
    const unsigned short* __restrict__ aoA,  // [4096 tokens][1024] bf16
    const float* __restrict__ bo,
    float* __restrict__ outF)                // [4096 tokens][1024] f32
{
    __shared__ __align__(16) unsigned short As[2][64*32];
    __shared__ __align__(16) unsigned short Bs[2][128*32];

    const int tid = threadIdx.x;
    const int w = tid >> 6, l = tid & 63;
    const int quad = l >> 4, l16 = l & 15;
    const int row0 = blockIdx.y * 64;    // out-channel tile
    const int col0 = blockIdx.x * 128;   // token tile

    f32x4 acc[4][2];
#pragma unroll
    for (int i = 0; i < 4; ++i)
#pragma unroll
        for (int j = 0; j < 2; ++j) acc[i][j] = (f32x4){0.f, 0.f, 0.f, 0.f};

    for (int k0 = 0; k0 < 1024; k0 += 64) {
        __syncthreads();
#pragma unroll
        for (int h = 0; h < 2; ++h) {
            {
                int m = tid >> 2, c = tid & 3;
                int cs = c ^ ((m >> 1) & 3);
                __builtin_amdgcn_global_load_lds(
                    GAS(woT + (size_t)(row0 + m)*1024 + k0 + h*32 + cs*8),
                    LAS(As[h] + (w*64)*8), 16, 0, 0);
            }
#pragma unroll
            for (int i = 0; i < 2; ++i) {
                int s = i*256 + tid;
                int m = s >> 2, c = s & 3;
                int cs = c ^ ((m >> 1) & 3);
                __builtin_amdgcn_global_load_lds(
                    GAS(aoA + (size_t)(col0 + m)*1024 + k0 + h*32 + cs*8),
                    LAS(Bs[h] + (i*256 + w*64)*8), 16, 0, 0);
            }
        }
        __syncthreads();

#pragma unroll
        for (int h = 0; h < 2; ++h) {
            bf16x8 af[4], bfr[2];
#pragma unroll
            for (int mt = 0; mt < 4; ++mt) {
                int m = mt*16 + l16;
                af[mt] = *reinterpret_cast<const bf16x8*>(As[h] + m*32 + (quad ^ ((m >> 1) & 3))*8);
            }
#pragma unroll
            for (int nt = 0; nt < 2; ++nt) {
                int n = w*32 + nt*16 + l16;
                bfr[nt] = *reinterpret_cast<const bf16x8*>(Bs[h] + n*32 + (quad ^ ((n >> 1) & 3))*8);
            }
#pragma unroll
            for (int mt = 0; mt < 4; ++mt)
#pragma unroll
                for (int nt = 0; nt < 2; ++nt)
                    acc[mt][nt] = __builtin_amdgcn_mfma_f32_16x16x32_bf16(
                        af[mt], bfr[nt], acc[mt][nt], 0, 0, 0);
        }
    }

#pragma unroll
    for (int mt = 0; mt < 4; ++mt) {
        int c = row0 + mt*16 + quad*4;
        float4 bv = *(const float4*)(bo + c);
#pragma unroll
        for (int nt = 0; nt < 2; ++nt) {
            int n = col0 + w*32 + nt*16 + l16;
            float4 ov = make_float4(acc[mt][nt][0] + bv.x, acc[mt][nt][1] + bv.y,
                                    acc[mt][nt][2] + bv.z, acc[mt][nt][3] + bv.w);
            *(float4*)(outF + (size_t)n*1024 + c) = ov;
        }
    }
}

// ---------------- kernel 3: flash attention (round-8 config, FROZEN) -----------
// Best measured: 50.28us (r8).  q-tile 128 (4 waves), kv-split (wave w owns
// q-half w&1 and kv-half w>>1; LDS reads halved), XCD swizzle (FETCH 69.7 ->
// 12.3 MB), 2 blocks/CU.  Declared converged: dependency-chain-bound
// (MFMA->exp2->permlane->PV + per-iter barrier skew); every resource knob
// measured over-provisioned.
// FAILED VARIANTS (do not retry): counted-vmcnt/3-buf (r2 null), 64q/wave in
// 2-wave blocks (r3 +22%), LDS-free reg-direct K/V (r5 +137%), q-tile 64 at
// 4 blocks/CU (r9 +1us, absmax worse).
__global__ __launch_bounds__(256, 2) void flash_attn(
    const unsigned short* __restrict__ qw,   // [B,H,N,64]  (pre-scaled)
    const unsigned short* __restrict__ kw,   // [B,H,M,64]
    const unsigned short* __restrict__ vtw,  // [B,H,64,M]
    unsigned short* __restrict__ ao)         // [B,N,H*64]
{
    __shared__ __align__(16) unsigned short Tile[2][9216];  // 2 x 18432 B

    const int tid = threadIdx.x;
    const int w = tid >> 6, l = tid & 63;
    const int quad = l >> 4, l16 = l & 15;
    // XCD-aware remap (grid (16,16,2) -> lin in [0,512))
    const int lin = (blockIdx.z * 16 + blockIdx.y) * 16 + blockIdx.x;
    const int bh = (lin & 7) * 4 + (lin >> 7);
    const int qt = (lin >> 3) & 15;
    const int qh = w & 1, kvh = w >> 1;
    const int q0 = qt * 128 + qh * 64;   // this wave's 64 queries

    int goff[5];
#pragma unroll
    for (int i = 0; i < 5; ++i) {
        int n = i*256 + w*64 + l;
        int m = (n < 576) ? n : n - 576;
        int row = m / 9, c = m % 9;  if (c > 7) c = 7;     // clamp pad chunk
        goff[i] = (n < 576) ? row*64 + c*8 : row*2048 + c*8;
    }
    const unsigned short* kbase = kw + (size_t)bh*131072;
    const unsigned short* vbase = vtw + (size_t)bh*131072;

    // Q as B-frag (K=32): B[n=q][k=d]; four 16-q groups
    bf16x8 qf[4][2];
#pragma unroll
    for (int qg = 0; qg < 4; ++qg)
#pragma unroll
        for (int s = 0; s < 2; ++s)
            qf[qg][s] = *reinterpret_cast<const bf16x8*>(
                qw + (size_t)(bh*2048 + q0 + qg*16 + l16)*64 + s*32 + quad*8);

    f32x4 accO[4][4];
#pragma unroll
    for (int qg = 0; qg < 4; ++qg)
#pragma unroll
        for (int td = 0; td < 4; ++td) accO[qg][td] = (f32x4){0.f, 0.f, 0.f, 0.f};
    float lpart[4] = {0.f, 0.f, 0.f, 0.f};

    const f32x4 zz = (f32x4){0.f, 0.f, 0.f, 0.f};

    // ---- preload tile 0 into buf 0
    {
#pragma unroll
        for (int i = 0; i < 4; ++i) {
            const unsigned short* bp = (i*4 + w < 9) ? kbase : vbase;
            __builtin_amdgcn_global_load_lds(GAS(bp + goff[i]),
                LAS(&Tile[0][(i*256 + w*64)*8]), 16, 0, 0);
        }
        if (w < 2)
            __builtin_amdgcn_global_load_lds(GAS(vbase + goff[4]),
                LAS(&Tile[0][(1024 + w*64)*8]), 16, 0, 0);
    }

    for (int it = 0; it < 32; ++it) {
        __syncthreads();   // drains vmcnt -> Tile[it&1] ready
        const int cur = it & 1;

        if (it + 1 < 32) {
            const unsigned short* kp = kbase + (it+1)*4096;
            const unsigned short* vp = vbase + (it+1)*64;
#pragma unroll
            for (int i = 0; i < 4; ++i) {
                const unsigned short* bp = (i*4 + w < 9) ? kp : vp;
                __builtin_amdgcn_global_load_lds(GAS(bp + goff[i]),
                    LAS(&Tile[cur^1][(i*256 + w*64)*8]), 16, 0, 0);
            }
            if (w < 2)
                __builtin_amdgcn_global_load_lds(GAS(vp + goff[4]),
                    LAS(&Tile[cur^1][(1024 + w*64)*8]), 16, 0, 0);
        }

        const unsigned short* Ks = &Tile[cur][0];
        const unsigned short* Vs = &Tile[cur][4608];

        // S^T = K Q^T over this wave's 32 kv rows: t = 0,1 (16 rows each)
        f32x4 sac[4][2];
        __builtin_amdgcn_s_setprio(1);
#pragma unroll
        for (int t = 0; t < 2; ++t) {
            const unsigned short* krow = Ks + (kvh*32 + t*16 + l16)*72 + quad*8;
            bf16x8 kf0 = *reinterpret_cast<const bf16x8*>(krow);
            bf16x8 kf1 = *reinterpret_cast<const bf16x8*>(krow + 32);
#pragma unroll
            for (int qg = 0; qg < 4; ++qg) {
                sac[qg][t] = __builtin_amdgcn_mfma_f32_16x16x32_bf16(kf0, qf[qg][0], zz, 0, 0, 0);
                sac[qg][t] = __builtin_amdgcn_mfma_f32_16x16x32_bf16(kf1, qf[qg][1], sac[qg][t], 0, 0, 0);
            }
        }
        __builtin_amdgcn_s_setprio(0);

        // P^T = exp2(S^T); fp32 partial row-sums; build one K=32 B-frag per qg
        u32x4v pB[4];
#pragma unroll
        for (int qg = 0; qg < 4; ++qg) {
            float pe0 = __builtin_amdgcn_exp2f(sac[qg][0][0]);
            float pe1 = __builtin_amdgcn_exp2f(sac[qg][0][1]);
            float pe2 = __builtin_amdgcn_exp2f(sac[qg][0][2]);
            float pe3 = __builtin_amdgcn_exp2f(sac[qg][0][3]);
            float po0 = __builtin_amdgcn_exp2f(sac[qg][1][0]);
            float po1 = __builtin_amdgcn_exp2f(sac[qg][1][1]);
            float po2 = __builtin_amdgcn_exp2f(sac[qg][1][2]);
            float po3 = __builtin_amdgcn_exp2f(sac[qg][1][3]);
            lpart[qg] += ((pe0 + po0) + (pe1 + po1)) + ((pe2 + po2) + (pe3 + po3));
            unsigned b0 = cvtpkbf(pe0, pe1), b1 = cvtpkbf(pe2, pe3);
            unsigned b2 = cvtpkbf(po0, po1), b3 = cvtpkbf(po2, po3);
            asm("v_permlane32_swap_b32 %0, %1" : "+v"(b0), "+v"(b2));
            asm("v_permlane16_swap_b32 %0, %1" : "+v"(b0), "+v"(b2));
            asm("v_permlane32_swap_b32 %0, %1" : "+v"(b1), "+v"(b3));
            asm("v_permlane16_swap_b32 %0, %1" : "+v"(b1), "+v"(b3));
            pB[qg] = (u32x4v){b0, b1, b2, b3};
        }

        // O^T += V^T P^T over this wave's 32 kv cols (k = kvh*32 + quad*8 + e)
        __builtin_amdgcn_s_setprio(1);
#pragma unroll
        for (int td = 0; td < 4; ++td) {
            bf16x8 vf = *reinterpret_cast<const bf16x8*>(
                Vs + (td*16 + l16)*72 + kvh*32 + quad*8);
#pragma unroll
            for (int qg = 0; qg < 4; ++qg)
                accO[qg][td] = __builtin_amdgcn_mfma_f32_16x16x32_bf16(
                    vf, __builtin_bit_cast(bf16x8, pB[qg]), accO[qg][td], 0, 0, 0);
        }
        __builtin_amdgcn_s_setprio(0);
    }

    // ---- cross-pair (kv-half) reduction through the dead Tile buffer.
    float* xch = (float*)&Tile[0][0];
    __syncthreads();   // all waves done reading Tile
    if (kvh == 1) {
        float* base = xch + (size_t)(qh*64 + l)*72;
#pragma unroll
        for (int qg = 0; qg < 4; ++qg)
#pragma unroll
            for (int td = 0; td < 4; ++td)
                *(f32x4*)(base + (qg*4 + td)*4) = accO[qg][td];
        *(f32x4*)(base + 64) = (f32x4){lpart[0], lpart[1], lpart[2], lpart[3]};
    }
    __syncthreads();
    if (kvh == 0) {
        const float* base = xch + (size_t)(qh*64 + l)*72;
#pragma unroll
        for (int qg = 0; qg < 4; ++qg)
#pragma unroll
            for (int td = 0; td < 4; ++td)
                accO[qg][td] += *(const f32x4*)(base + (qg*4 + td)*4);
        f32x4 lp2 = *(const f32x4*)(base + 64);
        lpart[0] += lp2[0]; lpart[1] += lp2[1];
        lpart[2] += lp2[2]; lpart[3] += lp2[3];

        // normalize + store this wave's 64 q rows
        const int bb = bh >> 4, hh = bh & 15;
#pragma unroll
        for (int qg = 0; qg < 4; ++qg) {
            float s = lpart[qg];
            s += __shfl_xor(s, 16);
            s += __shfl_xor(s, 32);
            float inv = 1.f / s;
            const size_t rowbase =
                (size_t)(bb*2048 + q0 + qg*16 + l16)*1024 + hh*64;
#pragma unroll
            for (int td = 0; td < 4; ++td)
#pragma unroll
                for (int r = 0; r < 4; ++r)
                    ao[rowbase + td*16 + quad*4 + r] = f2bf(accO[qg][td][r] * inv);
        }
    }
}

extern "C" void kernel_launch(void* const* d_in, const int* in_sizes, int n_in,
                              void* d_out, int out_size, void* d_ws, size_t ws_size,
                              hipStream_t stream)
{
    const float* x   = (const float*)d_in[0];
    const float* ctx = (const float*)d_in[1];
    const float* Wq  = (const float*)d_in[2];
    const float* Wk  = (const float*)d_in[3];
    const float* Wv  = (const float*)d_in[4];
    const float* Wo  = (const float*)d_in[5];
    const float* bo  = (const float*)d_in[6];
    float* out = (float*)d_out;

    unsigned short* ws  = (unsigned short*)d_ws;
    unsigned short* xb  = ws;
    unsigned short* cb  = ws + 4194304;
    unsigned short* wT  = ws + 8388608;
    unsigned short* qkv = ws + 12582912;
    unsigned short* ao  = ws;  // reuse xb space (xb dead after projections)

    prep<<<dim3(32, 32, 5), dim3(256), 0, stream>>>(x, ctx, Wq, Wk, Wv, Wo, xb, cb, wT);
    gemm128<<<dim3(32, 8, 3), dim3(256), 0, stream>>>(xb, cb, wT, ao, qkv, bo, out, 0);
    flash_attn<<<dim3(16, 16, 2), dim3(256), 0, stream>>>(qkv, qkv + 4194304, qkv + 8388608, ao);
    gemm_out<<<dim3(32, 16), dim3(256), 0, stream>>>(wT + 3*1048576, ao, bo, out);
}

// Round 12
// 197.484 us; speedup vs baseline: 1.0617x; 1.0133x over previous
//
#include <hip/hip_runtime.h>

// Problem constants
#define B_  2
#define N_  2048
#define M_  2048
#define D_  1024
#define H_  16
#define DH_ 64

typedef __bf16 bf16x8 __attribute__((ext_vector_type(8)));
typedef __bf16 bf16x4 __attribute__((ext_vector_type(4)));
typedef short  short4v __attribute__((ext_vector_type(4)));
typedef float  f32x4  __attribute__((ext_vector_type(4)));
typedef unsigned int u32x4v __attribute__((ext_vector_type(4)));

#define GAS(p) ((__attribute__((address_space(1))) void*)(p))
#define LAS(p) ((__attribute__((address_space(3))) void*)(p))

// SCALE * log2(e), folded into Q at projection time
#define QPRESCALE 0.18033688011112042f

__device__ __forceinline__ unsigned short f2bf(float f) {
    unsigned int u = __builtin_bit_cast(unsigned int, f);
    u += 0x7fffu + ((u >> 16) & 1u);   // round-to-nearest-even
    return (unsigned short)(u >> 16);
}

// pack two f32 -> one u32 of 2 bf16 (lo = a, hi = b), RNE
__device__ __forceinline__ unsigned cvtpkbf(float a, float b) {
    unsigned r;
    asm("v_cvt_pk_bf16_f32 %0, %1, %2" : "=v"(r) : "v"(a), "v"(b));
    return r;
}

// ------- kernel 1: prep = weight transpose+cast (z<4) | input cast (z==4) -------
__global__ __launch_bounds__(256) void prep(
    const float* __restrict__ x, const float* __restrict__ ctx,
    const float* __restrict__ Wq, const float* __restrict__ Wk,
    const float* __restrict__ Wv, const float* __restrict__ Wo,
    unsigned short* __restrict__ xb, unsigned short* __restrict__ cb,
    unsigned short* __restrict__ WTbase)
{
    if (blockIdx.z == 4) {
        int blk = blockIdx.y * 32 + blockIdx.x;
        int stride = 1024 * 256;
        for (int i = blk * 256 + threadIdx.x; i < 2097152; i += stride) {
            const float4* src; unsigned short* dst; int j;
            if (i < 1048576) { src = (const float4*)x;   dst = xb; j = i; }
            else             { src = (const float4*)ctx; dst = cb; j = i - 1048576; }
            float4 v = src[j];
            ushort4 o = make_ushort4(f2bf(v.x), f2bf(v.y), f2bf(v.z), f2bf(v.w));
            *(ushort4*)(dst + 4*j) = o;
        }
        return;
    }
    const float* W = (blockIdx.z == 0) ? Wq : (blockIdx.z == 1) ? Wk
                    : (blockIdx.z == 2) ? Wv : Wo;
    unsigned short* WT = WTbase + (size_t)blockIdx.z * 1048576;
    __shared__ unsigned short t[32][33];
    int tx = threadIdx.x & 31, ty8 = threadIdx.x >> 5;   // 32 x 8
    int c = blockIdx.x * 32 + tx;
#pragma unroll
    for (int i = 0; i < 4; ++i) {
        int r = blockIdx.y * 32 + i*8 + ty8;
        t[i*8 + ty8][tx] = f2bf(W[(size_t)r * 1024 + c]);
    }
    __syncthreads();
    int c2 = blockIdx.y * 32 + tx;
#pragma unroll
    for (int i = 0; i < 4; ++i) {
        int r2 = blockIdx.x * 32 + i*8 + ty8;
        WT[(size_t)r2 * 1024 + c2] = t[tx][i*8 + ty8];
    }
}

// ---------------- kernel 2: 128x128 bf16 GEMM, C = A * Bt^T (QKV modes) -------
// r7 structure (session-best total 198.6us): BK=64 -- two 32-wide K sub-tiles
// staged under one barrier pair, direct blockIdx mapping, no XCD swizzle.
// FAILED GEMM VARIANTS (do not retry): BK=32 2-phase stage-while-compute
// (r10, +9us), XCD swizzle (r8, +2us), counted-vmcnt on 2-barrier (m131 null).
// mode 0: A=WqT, Bt=xb  -> Q^T tile, stored [B,H,N,64] bf16 (*QPRESCALE), ushort4
// mode 1: A=WkT, Bt=cb  -> K^T tile, stored [B,H,M,64] bf16, ushort4
// mode 2: A=cb,  Bt=WvT -> V^T stored [B,H,64,M] bf16, ushort4 (original swap)
__global__ __launch_bounds__(256) void gemm128(
    const unsigned short* __restrict__ xb,
    const unsigned short* __restrict__ cb,
    const unsigned short* __restrict__ wT,
    const unsigned short* __restrict__ aoA,
    unsigned short* __restrict__ qkv_out,
    const float* __restrict__ bo,
    float* __restrict__ outF,
    int base_mode)
{
    __shared__ __align__(16) unsigned short As[2][128*32];
    __shared__ __align__(16) unsigned short Bs[2][128*32];

    const int mode = base_mode + blockIdx.z;
    const unsigned short* Amat;
    const unsigned short* Bt;
    if (mode == 0)      { Amat = wT;               Bt = xb; }
    else if (mode == 1) { Amat = wT + 1048576;     Bt = cb; }
    else                { Amat = cb;               Bt = wT + 2*1048576; }

    const int tid = threadIdx.x;
    const int w = tid >> 6, l = tid & 63;
    const int quad = l >> 4, l16 = l & 15;
    const int wm = w & 1, wn = w >> 1;
    int row0, col0;
    if (mode == 2) { row0 = blockIdx.x * 128; col0 = blockIdx.y * 128; }
    else           { row0 = blockIdx.y * 128; col0 = blockIdx.x * 128; }

    f32x4 acc[4][4];
#pragma unroll
    for (int i = 0; i < 4; ++i)
#pragma unroll
        for (int j = 0; j < 4; ++j) acc[i][j] = (f32x4){0.f, 0.f, 0.f, 0.f};

    for (int k0 = 0; k0 < 1024; k0 += 64) {
        __syncthreads();
#pragma unroll
        for (int h = 0; h < 2; ++h) {
#pragma unroll
            for (int i = 0; i < 2; ++i) {
                int s = i*256 + w*64 + l;
                int m = s >> 2, c = s & 3;
                int cs = c ^ ((m >> 1) & 3);
                __builtin_amdgcn_global_load_lds(
                    GAS(Amat + (size_t)(row0 + m)*1024 + k0 + h*32 + cs*8),
                    LAS(As[h] + (i*256 + w*64)*8), 16, 0, 0);
                __builtin_amdgcn_global_load_lds(
                    GAS(Bt + (size_t)(col0 + m)*1024 + k0 + h*32 + cs*8),
                    LAS(Bs[h] + (i*256 + w*64)*8), 16, 0, 0);
            }
        }
        __syncthreads();

#pragma unroll
        for (int h = 0; h < 2; ++h) {
            bf16x8 af[4], bfr[4];
#pragma unroll
            for (int mt = 0; mt < 4; ++mt) {
                int m = wm*64 + mt*16 + l16;
                af[mt] = *reinterpret_cast<const bf16x8*>(As[h] + m*32 + (quad ^ ((m >> 1) & 3))*8);
                int n = wn*64 + mt*16 + l16;
                bfr[mt] = *reinterpret_cast<const bf16x8*>(Bs[h] + n*32 + (quad ^ ((n >> 1) & 3))*8);
            }
#pragma unroll
            for (int mt = 0; mt < 4; ++mt)
#pragma unroll
                for (int nt = 0; nt < 4; ++nt)
                    acc[mt][nt] = __builtin_amdgcn_mfma_f32_16x16x32_bf16(
                        af[mt], bfr[nt], acc[mt][nt], 0, 0, 0);
        }
    }

    // Epilogues.  C/D layout: col = l16, row = quad*4 + r  [m89/m91 verified]
    if (mode == 2) {
        // V^T: [B,H,64,M]; r-direction = token n -> ushort4
#pragma unroll
        for (int mt = 0; mt < 4; ++mt) {
            int gr = row0 + wm*64 + mt*16 + quad*4;
            int b = gr >> 11, nidx = gr & 2047;
#pragma unroll
            for (int nt = 0; nt < 4; ++nt) {
                int col = col0 + wn*64 + nt*16 + l16;
                int h = col >> 6, d = col & 63;
                ushort4 pk = make_ushort4(f2bf(acc[mt][nt][0]), f2bf(acc[mt][nt][1]),
                                          f2bf(acc[mt][nt][2]), f2bf(acc[mt][nt][3]));
                *(ushort4*)(qkv_out + (size_t)2*4194304
                            + (size_t)((b*16 + h)*64 + d)*2048 + nidx) = pk;
            }
        }
    } else {
        // Q^T/K^T tile: row = channel c=(h,d) (4 consecutive d), col = token n
        const float qs = (mode == 0) ? QPRESCALE : 1.0f;
        unsigned short* obase = qkv_out + (size_t)mode*4194304;
#pragma unroll
        for (int nt = 0; nt < 4; ++nt) {
            int n = col0 + wn*64 + nt*16 + l16;
            int b = n >> 11, nidx = n & 2047;
#pragma unroll
            for (int mt = 0; mt < 4; ++mt) {
                int c = row0 + wm*64 + mt*16 + quad*4;
                int h = c >> 6, d = c & 63;
                ushort4 pkv = make_ushort4(
                    f2bf(acc[mt][nt][0] * qs), f2bf(acc[mt][nt][1] * qs),
                    f2bf(acc[mt][nt][2] * qs), f2bf(acc[mt][nt][3] * qs));
                *(ushort4*)(obase + (size_t)((b*16 + h)*2048 + nidx)*64 + d) = pkv;
            }
        }
    }
}

// ---------------- kernel 2b: out-projection GEMM, 64x128 tile, BK=64 ----------
// r7 structure (session-best): BK=64 under one barrier pair, no swizzle.
__global__ __launch_bounds__(256) void gemm_out(
    const unsigned short* __restrict__ woT,  // [1024 out-ch][1024 in] bf16
    const unsigned short* __restrict__ aoA,  // [4096 tokens][1024] bf16
    const float* __restrict__ bo,
    float* __restrict__ outF)                // [4096 tokens][1024] f32
{
    __shared__ __align__(16) unsigned short As[2][64*32];
    __shared__ __align__(16) unsigned short Bs[2][128*32];

    const int tid = threadIdx.x;
    const int w = tid >> 6, l = tid & 63;
    const int quad = l >> 4, l16 = l & 15;
    const int row0 = blockIdx.y * 64;    // out-channel tile
    const int col0 = blockIdx.x * 128;   // token tile

    f32x4 acc[4][2];
#pragma unroll
    for (int i = 0; i < 4; ++i)
#pragma unroll
        for (int j = 0; j < 2; ++j) acc[i][j] = (f32x4){0.f, 0.f, 0.f, 0.f};

    for (int k0 = 0; k0 < 1024; k0 += 64) {
        __syncthreads();
#pragma unroll
        for (int h = 0; h < 2; ++h) {
            {
                int m = tid >> 2, c = tid & 3;
                int cs = c ^ ((m >> 1) & 3);
                __builtin_amdgcn_global_load_lds(
                    GAS(woT + (size_t)(row0 + m)*1024 + k0 + h*32 + cs*8),
                    LAS(As[h] + (w*64)*8), 16, 0, 0);
            }
#pragma unroll
            for (int i = 0; i < 2; ++i) {
                int s = i*256 + tid;
                int m = s >> 2, c = s & 3;
                int cs = c ^ ((m >> 1) & 3);
                __builtin_amdgcn_global_load_lds(
                    GAS(aoA + (size_t)(col0 + m)*1024 + k0 + h*32 + cs*8),
                    LAS(Bs[h] + (i*256 + w*64)*8), 16, 0, 0);
            }
        }
        __syncthreads();

#pragma unroll
        for (int h = 0; h < 2; ++h) {
            bf16x8 af[4], bfr[2];
#pragma unroll
            for (int mt = 0; mt < 4; ++mt) {
                int m = mt*16 + l16;
                af[mt] = *reinterpret_cast<const bf16x8*>(As[h] + m*32 + (quad ^ ((m >> 1) & 3))*8);
            }
#pragma unroll
            for (int nt = 0; nt < 2; ++nt) {
                int n = w*32 + nt*16 + l16;
                bfr[nt] = *reinterpret_cast<const bf16x8*>(Bs[h] + n*32 + (quad ^ ((n >> 1) & 3))*8);
            }
#pragma unroll
            for (int mt = 0; mt < 4; ++mt)
#pragma unroll
                for (int nt = 0; nt < 2; ++nt)
                    acc[mt][nt] = __builtin_amdgcn_mfma_f32_16x16x32_bf16(
                        af[mt], bfr[nt], acc[mt][nt], 0, 0, 0);
        }
    }

#pragma unroll
    for (int mt = 0; mt < 4; ++mt) {
        int c = row0 + mt*16 + quad*4;
        float4 bv = *(const float4*)(bo + c);
#pragma unroll
        for (int nt = 0; nt < 2; ++nt) {
            int n = col0 + w*32 + nt*16 + l16;
            float4 ov = make_float4(acc[mt][nt][0] + bv.x, acc[mt][nt][1] + bv.y,
                                    acc[mt][nt][2] + bv.z, acc[mt][nt][3] + bv.w);
            *(float4*)(outF + (size_t)n*1024 + c) = ov;
        }
    }
}

// ---------------- kernel 3: flash attention (KVBLK=128, round-12) --------------
// ROUND-12 CHANGE (KV-tile 64 -> 128): accounting showed ~1300 cyc/iter of
// per-iteration FIXED cost (wall 3900 vs 2600 accounted issue) that survived
// all resource-side fixes (r2 drain, r7/r8 bandwidth, r3/r9 wave count).
// Doubling the KV tile halves the iteration count (32 -> 16 barriers), 2x
// work per barrier -- amortizes the fixed cost.  LDS layout: K = 128 rows x
// 72 ushort (slots [0,1152)), V^T = 64 rows x 136 ushort (slots [1152,2240));
// 35 KB/buffer x 2 = 70 KB, still 2 blocks/CU.  Staging 2240 slots = 9
// loads/thread (wave 3 skips its 9th, wave-uniform).  kv-split retained:
// wave w owns q-half (w&1) and kv-half (w>>1) = 64 of 128 rows; pB has 2
// frags/qg (one per 32-kv sub-window, same even/odd permlane recipe).
// XCD swizzle retained.  kv->wave regrouping changes reduction order
// (absmax may drift ~0.0007, r9 precedent: passed).
// FAILED VARIANTS (do not retry): counted-vmcnt/3-buf (r2 null), 64q/wave in
// 2-wave blocks (r3 +22%), LDS-free reg-direct K/V (r5 +137%), q-tile 64 at
// 4 blocks/CU (r9 null).
__global__ __launch_bounds__(256, 2) void flash_attn(
    const unsigned short* __restrict__ qw,   // [B,H,N,64]  (pre-scaled)
    const unsigned short* __restrict__ kw,   // [B,H,M,64]
    const unsigned short* __restrict__ vtw,  // [B,H,64,M]
    unsigned short* __restrict__ ao)         // [B,N,H*64]
{
    __shared__ __align__(16) unsigned short Tile[2][17920];  // 2 x 35840 B

    const int tid = threadIdx.x;
    const int w = tid >> 6, l = tid & 63;
    const int quad = l >> 4, l16 = l & 15;
    // XCD-aware remap (grid (16,16,2) -> lin in [0,512))
    const int lin = (blockIdx.z * 16 + blockIdx.y) * 16 + blockIdx.x;
    const int bh = (lin & 7) * 4 + (lin >> 7);
    const int qt = (lin >> 3) & 15;
    const int qh = w & 1, kvh = w >> 1;
    const int q0 = qt * 128 + qh * 64;   // this wave's 64 queries

    // staging offsets: slot n = i*256 + w*64 + l; K slots [0,1152), V [1152,2240)
    int goff[9];
#pragma unroll
    for (int i = 0; i < 9; ++i) {
        int n = i*256 + w*64 + l;
        if (n < 1152) {
            int row = n / 9, c = n % 9;  if (c > 7) c = 7;      // pad chunk clamp
            goff[i] = row*64 + c*8;                              // from kp
        } else {
            int m = n - 1152;
            int d = m / 17, cc = m % 17;  if (cc > 15) cc = 15;  // pad chunk clamp
            goff[i] = d*2048 + cc*8;                             // from vp
        }
    }
    const unsigned short* kbase = kw + (size_t)bh*131072;
    const unsigned short* vbase = vtw + (size_t)bh*131072;

    // Q as B-frag (K=32): B[n=q][k=d]; four 16-q groups
    bf16x8 qf[4][2];
#pragma unroll
    for (int qg = 0; qg < 4; ++qg)
#pragma unroll
        for (int s = 0; s < 2; ++s)
            qf[qg][s] = *reinterpret_cast<const bf16x8*>(
                qw + (size_t)(bh*2048 + q0 + qg*16 + l16)*64 + s*32 + quad*8);

    f32x4 accO[4][4];
#pragma unroll
    for (int qg = 0; qg < 4; ++qg)
#pragma unroll
        for (int td = 0; td < 4; ++td) accO[qg][td] = (f32x4){0.f, 0.f, 0.f, 0.f};
    float lpart[4] = {0.f, 0.f, 0.f, 0.f};

    const f32x4 zz = (f32x4){0.f, 0.f, 0.f, 0.f};

    // issue one 128-row KV tile's global->LDS loads into buffer b
    auto issue_tile = [&](int it, int b) {
        const unsigned short* kp = kbase + it*8192;   // 128 rows x 64
        const unsigned short* vp = vbase + it*128;    // col offset in V^T
#pragma unroll
        for (int i = 0; i < 9; ++i) {
            int nb = i*256 + w*64;                    // wave-uniform slot base
            if (nb >= 2240) continue;                 // wave 3's 9th: no slot
            const unsigned short* bp = (nb < 1152) ? kp : vp;
            __builtin_amdgcn_global_load_lds(GAS(bp + goff[i]),
                LAS(&Tile[b][nb*8]), 16, 0, 0);
        }
    };

    issue_tile(0, 0);

    for (int it = 0; it < 16; ++it) {
        __syncthreads();   // drains vmcnt -> Tile[it&1] ready
        const int cur = it & 1;

        if (it + 1 < 16) issue_tile(it + 1, cur ^ 1);

        const unsigned short* Ks = &Tile[cur][0];
        const unsigned short* Vs = &Tile[cur][9216];

        // S^T = K Q^T over this wave's 64 kv rows: t = 0..3 (16 rows each)
        f32x4 sac[4][4];
        __builtin_amdgcn_s_setprio(1);
#pragma unroll
        for (int t = 0; t < 4; ++t) {
            const unsigned short* krow = Ks + (kvh*64 + t*16 + l16)*72 + quad*8;
            bf16x8 kf0 = *reinterpret_cast<const bf16x8*>(krow);
            bf16x8 kf1 = *reinterpret_cast<const bf16x8*>(krow + 32);
#pragma unroll
            for (int qg = 0; qg < 4; ++qg) {
                sac[qg][t] = __builtin_amdgcn_mfma_f32_16x16x32_bf16(kf0, qf[qg][0], zz, 0, 0, 0);
                sac[qg][t] = __builtin_amdgcn_mfma_f32_16x16x32_bf16(kf1, qf[qg][1], sac[qg][t], 0, 0, 0);
            }
        }
        __builtin_amdgcn_s_setprio(0);

        // P^T = exp2(S^T); fp32 partial row-sums; two K=32 B-frags per qg
        // (sub-window s covers kv rows kvh*64 + s*32 + [0,32): t = 2s even,
        //  t = 2s+1 odd -> same permlane quad-redistribution as before)
        u32x4v pB[4][2];
#pragma unroll
        for (int qg = 0; qg < 4; ++qg) {
#pragma unroll
            for (int s = 0; s < 2; ++s) {
                float pe0 = __builtin_amdgcn_exp2f(sac[qg][2*s][0]);
                float pe1 = __builtin_amdgcn_exp2f(sac[qg][2*s][1]);
                float pe2 = __builtin_amdgcn_exp2f(sac[qg][2*s][2]);
                float pe3 = __builtin_amdgcn_exp2f(sac[qg][2*s][3]);
                float po0 = __builtin_amdgcn_exp2f(sac[qg][2*s+1][0]);
                float po1 = __builtin_amdgcn_exp2f(sac[qg][2*s+1][1]);
                float po2 = __builtin_amdgcn_exp2f(sac[qg][2*s+1][2]);
                float po3 = __builtin_amdgcn_exp2f(sac[qg][2*s+1][3]);
                lpart[qg] += ((pe0 + po0) + (pe1 + po1)) + ((pe2 + po2) + (pe3 + po3));
                unsigned b0 = cvtpkbf(pe0, pe1), b1 = cvtpkbf(pe2, pe3);
                unsigned b2 = cvtpkbf(po0, po1), b3 = cvtpkbf(po2, po3);
                asm("v_permlane32_swap_b32 %0, %1" : "+v"(b0), "+v"(b2));
                asm("v_permlane16_swap_b32 %0, %1" : "+v"(b0), "+v"(b2));
                asm("v_permlane32_swap_b32 %0, %1" : "+v"(b1), "+v"(b3));
                asm("v_permlane16_swap_b32 %0, %1" : "+v"(b1), "+v"(b3));
                pB[qg][s] = (u32x4v){b0, b1, b2, b3};
            }
        }

        // O^T += V^T P^T over this wave's 64 kv cols (k = kvh*64 + s*32 + quad*8 + e)
        __builtin_amdgcn_s_setprio(1);
#pragma unroll
        for (int td = 0; td < 4; ++td) {
            const unsigned short* vrow = Vs + (td*16 + l16)*136 + kvh*64 + quad*8;
            bf16x8 vf0 = *reinterpret_cast<const bf16x8*>(vrow);
            bf16x8 vf1 = *reinterpret_cast<const bf16x8*>(vrow + 32);
#pragma unroll
            for (int qg = 0; qg < 4; ++qg) {
                accO[qg][td] = __builtin_amdgcn_mfma_f32_16x16x32_bf16(
                    vf0, __builtin_bit_cast(bf16x8, pB[qg][0]), accO[qg][td], 0, 0, 0);
                accO[qg][td] = __builtin_amdgcn_mfma_f32_16x16x32_bf16(
                    vf1, __builtin_bit_cast(bf16x8, pB[qg][1]), accO[qg][td], 0, 0, 0);
            }
        }
        __builtin_amdgcn_s_setprio(0);
    }

    // ---- cross-pair (kv-half) reduction through the dead Tile buffer.
    // Layout per q-half: 64 lanes x 72 f32 (stride 72, 16B-aligned):
    //   [0..63] = accO (16 x f32x4), [64..67] = lpart.  2 regions = 36 KB.
    float* xch = (float*)&Tile[0][0];
    __syncthreads();   // all waves done reading Tile
    if (kvh == 1) {
        float* base = xch + (size_t)(qh*64 + l)*72;
#pragma unroll
        for (int qg = 0; qg < 4; ++qg)
#pragma unroll
            for (int td = 0; td < 4; ++td)
                *(f32x4*)(base + (qg*4 + td)*4) = accO[qg][td];
        *(f32x4*)(base + 64) = (f32x4){lpart[0], lpart[1], lpart[2], lpart[3]};
    }
    __syncthreads();
    if (kvh == 0) {
        const float* base = xch + (size_t)(qh*64 + l)*72;
#pragma unroll
        for (int qg = 0; qg < 4; ++qg)
#pragma unroll
            for (int td = 0; td < 4; ++td)
                accO[qg][td] += *(const f32x4*)(base + (qg*4 + td)*4);
        f32x4 lp2 = *(const f32x4*)(base + 64);
        lpart[0] += lp2[0]; lpart[1] += lp2[1];
        lpart[2] += lp2[2]; lpart[3] += lp2[3];

        // normalize + store this wave's 64 q rows
        const int bb = bh >> 4, hh = bh & 15;
#pragma unroll
        for (int qg = 0; qg < 4; ++qg) {
            float s = lpart[qg];
            s += __shfl_xor(s, 16);
            s += __shfl_xor(s, 32);
            float inv = 1.f / s;
            const size_t rowbase =
                (size_t)(bb*2048 + q0 + qg*16 + l16)*1024 + hh*64;
#pragma unroll
            for (int td = 0; td < 4; ++td)
#pragma unroll
                for (int r = 0; r < 4; ++r)
                    ao[rowbase + td*16 + quad*4 + r] = f2bf(accO[qg][td][r] * inv);
        }
    }
}

extern "C" void kernel_launch(void* const* d_in, const int* in_sizes, int n_in,
                              void* d_out, int out_size, void* d_ws, size_t ws_size,
                              hipStream_t stream)
{
    const float* x   = (const float*)d_in[0];
    const float* ctx = (const float*)d_in[1];
    const float* Wq  = (const float*)d_in[2];
    const float* Wk  = (const float*)d_in[3];
    const float* Wv  = (const float*)d_in[4];
    const float* Wo  = (const float*)d_in[5];
    const float* bo  = (const float*)d_in[6];
    float* out = (float*)d_out;

    unsigned short* ws  = (unsigned short*)d_ws;
    unsigned short* xb  = ws;
    unsigned short* cb  = ws + 4194304;
    unsigned short* wT  = ws + 8388608;
    unsigned short* qkv = ws + 12582912;
    unsigned short* ao  = ws;  // reuse xb space (xb dead after projections)

    prep<<<dim3(32, 32, 5), dim3(256), 0, stream>>>(x, ctx, Wq, Wk, Wv, Wo, xb, cb, wT);
    gemm128<<<dim3(32, 8, 3), dim3(256), 0, stream>>>(xb, cb, wT, ao, qkv, bo, out, 0);
    flash_attn<<<dim3(16, 16, 2), dim3(256), 0, stream>>>(qkv, qkv + 4194304, qkv + 8388608, ao);
    gemm_out<<<dim3(32, 16), dim3(256), 0, stream>>>(wT + 3*1048576, ao, bo, out);
}